// Round 6
// baseline (77.669 us; speedup 1.0000x reference)
//
#include <hip/hip_runtime.h>
#include <hip/hip_bf16.h>

typedef __attribute__((ext_vector_type(4))) float f32x4;
typedef __attribute__((ext_vector_type(4))) unsigned int u32x4;
typedef __attribute__((ext_vector_type(8))) __bf16 bf16x8;
using u16 = unsigned short;

namespace {
constexpr int T_ = 4096;
constexpr int K_ = 2048;
constexpr int N_ = 1024;
constexpr int E_ = 8;
constexpr int BM = 128, BN = 128, BK = 32;
constexpr int LSTR = BK + 8;                     // fallback (reg-staging) LDS stride
constexpr size_t PART_ELEMS = (size_t)T_ * N_;   // 4M floats per partial plane
constexpr size_t XB_ELEMS = (size_t)T_ * K_;     // 8M bf16
constexpr size_t WB_ELEMS = (size_t)E_ * N_ * K_;// 16M bf16
}

__device__ __forceinline__ unsigned int pk2(float a, float b) {
    union { __hip_bfloat162 h; unsigned int u; } c;
    c.h = __float22bfloat162_rn(make_float2(a, b));   // v_cvt_pk_bf16_f32
    return c.u;
}

__device__ __forceinline__ u32x4 cvt8(f32x4 a, f32x4 b) {
    u32x4 r;
    r.x = pk2(a.x, a.y);
    r.y = pk2(a.z, a.w);
    r.z = pk2(b.x, b.y);
    r.w = pk2(b.z, b.w);
    return r;
}

// Async global(bf16)->LDS, 16B per lane. Dest must be wave-uniform base + lane*16.
__device__ __forceinline__ void gld16(const u16* g, u16* l) {
    __builtin_amdgcn_global_load_lds(
        (const __attribute__((address_space(1))) void*)g,
        (__attribute__((address_space(3))) void*)l, 16, 0, 0);
}

// ---------------- prepass: fp32 -> bf16 (packed pairs) ----------------
__global__ __launch_bounds__(256) void cvt_bf16_kernel(
        const float* __restrict__ in, unsigned int* __restrict__ out, int n8) {
    const int stride = gridDim.x * blockDim.x;
    for (int i = blockIdx.x * blockDim.x + threadIdx.x; i < n8; i += stride) {
        const f32x4 a = ((const f32x4*)in)[2 * i];
        const f32x4 b = ((const f32x4*)in)[2 * i + 1];
        ((u32x4*)out)[i] = cvt8(a, b);
    }
}

// ---------------- main GEMM: bf16 source, global_load_lds staging ----------------
// m97 structure: linear [128][32] bf16 LDS tiles (gload_lds requires linear dest;
// 64B rows keep fragment ds_read_b128 at <=2-way bank aliasing), double-buffered,
// one barrier per K-step. No staging VGPRs, no in-loop cvt.
template <int KSPLIT>
__global__ __launch_bounds__(256) void gg_lds_kernel(
        const u16* __restrict__ xb, const u16* __restrict__ wb,
        const int* __restrict__ offs, float* __restrict__ out) {
    constexpr int KCH = K_ / KSPLIT;
    constexpr int NKS = KCH / BK;
    __shared__ __align__(16) u16 As[2][BM * BK];   // 8 KB per buffer
    __shared__ __align__(16) u16 Bs[2][BN * BK];   // total 32 KB -> 5 blocks/CU

    const int tid = threadIdx.x;
    const int lane = tid & 63;
    const int wid = tid >> 6;
    const int wr = wid >> 1, wc = wid & 1;  // 2x2 wave grid, 64x64 out per wave

    // XCD decode: b&7 = XCD = expert (equal split); per-XCD working set is one
    // expert's bf16 panel (w_e 4MB + x_e 2MB) ~ L2-resident.
    const int b = blockIdx.x;
    const int xcd = b & 7;
    const int inner = b >> 3;                 // 0 .. 32*KSPLIT-1
    const int ks = inner >> 5;                // 0 .. KSPLIT-1
    const int rem = inner & 31;
    const int by = xcd * 4 + (rem >> 3);      // 0..31
    const int bx = rem & 7;                   // 0..7
    const int brow = by * BM;
    const int bcol = bx * BN;
    const int k0 = ks * KCH;

    float* outp = out + (size_t)ks * PART_ELEMS;

    // gload mapping: thread tid covers row tid>>2 (0..63), 16B col chunk (tid&3)*8.
    // LDS offset tid*16B == row-major [64][32] u16 -> linear in lane order. Second
    // issue covers rows 64..127 at +4KB.
    const int grow = tid >> 2;
    const int gcol = (tid & 3) * 8;
    const u16* aS = xb + (size_t)(brow + grow) * K_ + k0 + gcol;

    // MFMA fragment offsets: lane holds row/col = lane&15, k = 8*(lane>>4)..+7
    const int frow = lane & 15;
    const int fk = (lane >> 4) * 8;
    const int aF = (wr * 64 + frow) * BK + fk;
    const int bF = (wc * 64 + frow) * BK + fk;

#define STAGE(t, buf)                                                  \
    do {                                                               \
        const u16* _a = aS + (t) * BK;                                 \
        const u16* _b = bS + (t) * BK;                                 \
        gld16(_a,                   &As[buf][tid * 8]);                \
        gld16(_a + (size_t)64 * K_, &As[buf][2048 + tid * 8]);         \
        gld16(_b,                   &Bs[buf][tid * 8]);                \
        gld16(_b + (size_t)64 * K_, &Bs[buf][2048 + tid * 8]);         \
    } while (0)

    for (int e = 0; e < E_; ++e) {
        const int s = (e == 0) ? 0 : offs[e - 1];
        const int en = offs[e];
        if (en <= brow || s >= brow + BM) continue;  // block-uniform

        const u16* bS = wb + ((size_t)e * N_ + bcol + grow) * K_ + k0 + gcol;

        STAGE(0, 0);
        __syncthreads();   // compiler drains vmcnt(0) before s_barrier

        f32x4 acc[4][4];
#pragma unroll
        for (int m = 0; m < 4; ++m)
#pragma unroll
            for (int n = 0; n < 4; ++n)
                acc[m][n] = f32x4{0.0f, 0.0f, 0.0f, 0.0f};

        for (int t = 0; t < NKS; ++t) {
            const int cur = t & 1;
            if (t + 1 < NKS) STAGE(t + 1, cur ^ 1);  // async, in flight across MFMA
            bf16x8 af[4], bg[4];
#pragma unroll
            for (int m = 0; m < 4; ++m)
                af[m] = *(const bf16x8*)&As[cur][aF + m * 16 * BK];
#pragma unroll
            for (int n = 0; n < 4; ++n)
                bg[n] = *(const bf16x8*)&Bs[cur][bF + n * 16 * BK];
#pragma unroll
            for (int m = 0; m < 4; ++m)
#pragma unroll
                for (int n = 0; n < 4; ++n)
                    acc[m][n] = __builtin_amdgcn_mfma_f32_16x16x32_bf16(
                        af[m], bg[n], acc[m][n], 0, 0, 0);
            __syncthreads();
        }

        // C/D layout: col = lane&15, row = (lane>>4)*4 + reg
        const int cb = bcol + wc * 64 + frow;
#pragma unroll
        for (int m = 0; m < 4; ++m) {
            const int r0 = brow + wr * 64 + m * 16 + (lane >> 4) * 4;
#pragma unroll
            for (int r = 0; r < 4; ++r) {
                const int row = r0 + r;
                if (row < s || row >= en) continue;  // ragged-boundary mask
                float* yp = outp + (size_t)row * N_ + cb;
#pragma unroll
                for (int n = 0; n < 4; ++n) yp[n * 16] = acc[m][n][r];
            }
        }
        __syncthreads();  // uniform; protects LDS reuse across expert passes
    }
#undef STAGE
}

// ---------------- fallback: fp32 reg-staging kernel (round-5) ----------------
template <int KSPLIT, int ATOMIC>
__global__ __launch_bounds__(256, 3) void gg_bf16_kernel(
        const float* __restrict__ x, const float* __restrict__ w,
        const int* __restrict__ offs, float* __restrict__ out) {
    constexpr int KCH = K_ / KSPLIT;
    constexpr int NKS = KCH / BK;
    __shared__ __align__(16) u16 As[2][BM * LSTR];
    __shared__ __align__(16) u16 Bs[2][BN * LSTR];

    const int tid = threadIdx.x;
    const int lane = tid & 63;
    const int wid = tid >> 6;
    const int wr = wid >> 1, wc = wid & 1;

    const int b = blockIdx.x;
    const int xcd = b & 7;
    const int inner = b >> 3;
    const int ks = inner >> 5;
    const int rem = inner & 31;
    const int by = xcd * 4 + (rem >> 3);
    const int bx = rem & 7;
    const int brow = by * BM;
    const int bcol = bx * BN;
    const int k0 = ks * KCH;

    float* outp = ATOMIC ? out : (out + (size_t)ks * PART_ELEMS);

    const int srow = tid >> 2;
    const int scol = (tid & 3) * 8;
    const float* aB0 = x + (size_t)(brow + srow) * K_ + k0 + scol;
    const float* aB1 = aB0 + (size_t)64 * K_;
    const int ldsO0 = srow * LSTR + scol;
    const int ldsO1 = (srow + 64) * LSTR + scol;

    const int frow = lane & 15;
    const int fk = (lane >> 4) * 8;
    const int aF = (wr * 64 + frow) * LSTR + fk;
    const int bF = (wc * 64 + frow) * LSTR + fk;

#define LOADT(t)                                                      \
    do {                                                              \
        const float* _a0 = aB0 + (t) * BK;                            \
        const float* _a1 = aB1 + (t) * BK;                            \
        const float* _b0 = bB0 + (t) * BK;                            \
        const float* _b1 = bB1 + (t) * BK;                            \
        ra0 = *(const f32x4*)_a0; ra1 = *(const f32x4*)(_a0 + 4);     \
        ra2 = *(const f32x4*)_a1; ra3 = *(const f32x4*)(_a1 + 4);     \
        rb0 = *(const f32x4*)_b0; rb1 = *(const f32x4*)(_b0 + 4);     \
        rb2 = *(const f32x4*)_b1; rb3 = *(const f32x4*)(_b1 + 4);     \
    } while (0)

#define STORET(buf)                                                   \
    do {                                                              \
        *(u32x4*)&As[buf][ldsO0] = cvt8(ra0, ra1);                    \
        *(u32x4*)&As[buf][ldsO1] = cvt8(ra2, ra3);                    \
        *(u32x4*)&Bs[buf][ldsO0] = cvt8(rb0, rb1);                    \
        *(u32x4*)&Bs[buf][ldsO1] = cvt8(rb2, rb3);                    \
    } while (0)

    for (int e = 0; e < E_; ++e) {
        const int s = (e == 0) ? 0 : offs[e - 1];
        const int en = offs[e];
        if (en <= brow || s >= brow + BM) continue;

        const float* bB0 = w + ((size_t)e * N_ + bcol + srow) * K_ + k0 + scol;
        const float* bB1 = bB0 + (size_t)64 * K_;

        f32x4 ra0, ra1, ra2, ra3, rb0, rb1, rb2, rb3;
        LOADT(0);
        STORET(0);
        LOADT(1);
        __syncthreads();

        f32x4 acc[4][4];
#pragma unroll
        for (int m = 0; m < 4; ++m)
#pragma unroll
            for (int n = 0; n < 4; ++n)
                acc[m][n] = f32x4{0.0f, 0.0f, 0.0f, 0.0f};

        for (int t = 0; t < NKS; ++t) {
            const int cur = t & 1;
            if (t + 1 < NKS) STORET(cur ^ 1);
            if (t + 2 < NKS) LOADT(t + 2);
            bf16x8 af[4], bg[4];
#pragma unroll
            for (int m = 0; m < 4; ++m)
                af[m] = *(const bf16x8*)&As[cur][aF + m * 16 * LSTR];
#pragma unroll
            for (int n = 0; n < 4; ++n)
                bg[n] = *(const bf16x8*)&Bs[cur][bF + n * 16 * LSTR];
#pragma unroll
            for (int m = 0; m < 4; ++m)
#pragma unroll
                for (int n = 0; n < 4; ++n)
                    acc[m][n] = __builtin_amdgcn_mfma_f32_16x16x32_bf16(
                        af[m], bg[n], acc[m][n], 0, 0, 0);
            __syncthreads();
        }

        const int cb = bcol + wc * 64 + frow;
#pragma unroll
        for (int m = 0; m < 4; ++m) {
            const int r0 = brow + wr * 64 + m * 16 + (lane >> 4) * 4;
#pragma unroll
            for (int r = 0; r < 4; ++r) {
                const int row = r0 + r;
                if (row < s || row >= en) continue;
                float* yp = outp + (size_t)row * N_ + cb;
#pragma unroll
                for (int n = 0; n < 4; ++n) {
                    if (ATOMIC) atomicAdd(&yp[n * 16], acc[m][n][r]);
                    else        yp[n * 16] = acc[m][n][r];
                }
            }
        }
        __syncthreads();
    }
#undef LOADT
#undef STORET
}

template <int P>
__global__ __launch_bounds__(256) void gg_reduce_kernel(
        const float* __restrict__ part, float* __restrict__ y) {
    const size_t i = (size_t)blockIdx.x * blockDim.x + threadIdx.x;  // f32x4 idx
    f32x4 acc = ((const f32x4*)part)[i];
#pragma unroll
    for (int p = 1; p < P; ++p)
        acc += ((const f32x4*)(part + (size_t)p * PART_ELEMS))[i];
    ((f32x4*)y)[i] = acc;
}

extern "C" void kernel_launch(void* const* d_in, const int* in_sizes, int n_in,
                              void* d_out, int out_size, void* d_ws, size_t ws_size,
                              hipStream_t stream) {
    const float* x = (const float*)d_in[0];
    const float* w = (const float*)d_in[1];
    const int* offs = (const int*)d_in[2];
    float* y = (float*)d_out;
    float* part = (float*)d_ws;
    const int rgrid = (int)(PART_ELEMS / 4 / 256);

    // ws layout (full tier): [KSPLIT partial planes f32][xb bf16][wb bf16]
    const size_t bf16_bytes = (XB_ELEMS + WB_ELEMS) * sizeof(u16);  // 48 MB
    const size_t need4 = 4 * PART_ELEMS * sizeof(float) + bf16_bytes;  // 112 MB
    const size_t need2 = 2 * PART_ELEMS * sizeof(float) + bf16_bytes;  // 80 MB

    if (ws_size >= need4 || ws_size >= need2) {
        const int ksplit = (ws_size >= need4) ? 4 : 2;
        u16* xb = (u16*)(part + (size_t)ksplit * PART_ELEMS);
        u16* wb = xb + XB_ELEMS;
        cvt_bf16_kernel<<<dim3(2048), dim3(256), 0, stream>>>(
            x, (unsigned int*)xb, (int)(XB_ELEMS / 8));
        cvt_bf16_kernel<<<dim3(2048), dim3(256), 0, stream>>>(
            w, (unsigned int*)wb, (int)(WB_ELEMS / 8));
        if (ksplit == 4) {
            gg_lds_kernel<4><<<dim3(1024), dim3(256), 0, stream>>>(xb, wb, offs, part);
            gg_reduce_kernel<4><<<dim3(rgrid), dim3(256), 0, stream>>>(part, y);
        } else {
            gg_lds_kernel<2><<<dim3(512), dim3(256), 0, stream>>>(xb, wb, offs, part);
            gg_reduce_kernel<2><<<dim3(rgrid), dim3(256), 0, stream>>>(part, y);
        }
    } else if (ws_size >= 4 * PART_ELEMS * sizeof(float)) {
        gg_bf16_kernel<4, 0><<<dim3(1024), dim3(256), 0, stream>>>(x, w, offs, part);
        gg_reduce_kernel<4><<<dim3(rgrid), dim3(256), 0, stream>>>(part, y);
    } else if (ws_size >= 2 * PART_ELEMS * sizeof(float)) {
        gg_bf16_kernel<2, 0><<<dim3(512), dim3(256), 0, stream>>>(x, w, offs, part);
        gg_reduce_kernel<2><<<dim3(rgrid), dim3(256), 0, stream>>>(part, y);
    } else {
        hipMemsetAsync(d_out, 0, PART_ELEMS * sizeof(float), stream);
        gg_bf16_kernel<2, 1><<<dim3(512), dim3(256), 0, stream>>>(x, w, offs, y);
    }
}

// Round 7
// 65.086 us; speedup vs baseline: 1.1933x; 1.1933x over previous
//
#include <hip/hip_runtime.h>
#include <hip/hip_bf16.h>

typedef __attribute__((ext_vector_type(4))) float f32x4;
typedef __attribute__((ext_vector_type(4))) unsigned int u32x4;
typedef __attribute__((ext_vector_type(8))) __bf16 bf16x8;
using u16 = unsigned short;

namespace {
constexpr int T_ = 4096;
constexpr int K_ = 2048;
constexpr int N_ = 1024;
constexpr int E_ = 8;
constexpr int BM = 128, BN = 128, BK = 32;
constexpr int LSTR = BK + 8;                     // fallback kernel LDS stride
constexpr size_t PART_ELEMS = (size_t)T_ * N_;   // 4M floats per partial plane
constexpr size_t XB_ELEMS = (size_t)T_ * K_;     // 8M bf16
constexpr size_t WB_ELEMS = (size_t)E_ * N_ * K_;// 16M bf16
}

__device__ __forceinline__ unsigned int pk2(float a, float b) {
    union { __hip_bfloat162 h; unsigned int u; } c;
    c.h = __float22bfloat162_rn(make_float2(a, b));   // v_cvt_pk_bf16_f32
    return c.u;
}

__device__ __forceinline__ u32x4 cvt8(f32x4 a, f32x4 b) {
    u32x4 r;
    r.x = pk2(a.x, a.y);
    r.y = pk2(a.z, a.w);
    r.z = pk2(b.x, b.y);
    r.w = pk2(b.z, b.w);
    return r;
}

__device__ __forceinline__ void gld16(const u16* g, u16* l) {
    __builtin_amdgcn_global_load_lds(
        (const __attribute__((address_space(1))) void*)g,
        (__attribute__((address_space(3))) void*)l, 16, 0, 0);
}

// ---------------- fused prepass: x and w fp32 -> bf16, one launch ----------------
__global__ __launch_bounds__(256) void cvt_all_kernel(
        const float* __restrict__ x, const float* __restrict__ w,
        unsigned int* __restrict__ xb, unsigned int* __restrict__ wb) {
    const long long nx = (long long)(XB_ELEMS / 8);        // 1M u32x4 units
    const long long tot = nx + (long long)(WB_ELEMS / 8);  // 3M
    const long long stride = (long long)gridDim.x * blockDim.x;
    for (long long i = (long long)blockIdx.x * blockDim.x + threadIdx.x;
         i < tot; i += stride) {
        if (i < nx) {
            const f32x4 a = ((const f32x4*)x)[2 * i];
            const f32x4 b = ((const f32x4*)x)[2 * i + 1];
            ((u32x4*)xb)[i] = cvt8(a, b);
        } else {
            const long long j = i - nx;
            const f32x4 a = ((const f32x4*)w)[2 * j];
            const f32x4 b = ((const f32x4*)w)[2 * j + 1];
            ((u32x4*)wb)[j] = cvt8(a, b);
        }
    }
}

// ---------------- main GEMM: counted-vmcnt 3-buffer pipeline ----------------
// LDS tile [128][32] bf16 (64B rows). Chunk-XOR swizzle (16B units):
//   LDS[row][cp] holds logical[row][cp ^ ((row>>1)&3)]
// realized by XOR-ing the per-lane GLOBAL source chunk (linear gload_lds dest,
// rule 21) and the same XOR on the ds_read side. Fragment-read bank spread
// becomes 2-way (free). K-loop never drains vmcnt to 0 (T4): 2 tiles in
// flight, vmcnt(8) steady state, raw s_barrier (no compiler drain).
template <int KSPLIT>
__global__ __launch_bounds__(256) void gg_lds_kernel(
        const u16* __restrict__ xb, const u16* __restrict__ wb,
        const int* __restrict__ offs, float* __restrict__ out) {
    constexpr int KCH = K_ / KSPLIT;
    constexpr int NKS = KCH / BK;                 // 32 at KSPLIT=2
    __shared__ __align__(16) u16 As[3][BM * BK];  // 3 x 8 KB
    __shared__ __align__(16) u16 Bs[3][BN * BK];  // 48 KB total

    const int tid = threadIdx.x;
    const int lane = tid & 63;
    const int wid = tid >> 6;
    const int wr = wid >> 1, wc = wid & 1;        // 2x2 waves, 64x64 out each

    const int b = blockIdx.x;
    const int xcd = b & 7;
    const int inner = b >> 3;
    const int ks = inner >> 5;
    const int rem = inner & 31;
    const int by = xcd * 4 + (rem >> 3);
    const int bx = rem & 7;
    const int brow = by * BM;
    const int bcol = bx * BN;
    const int k0 = ks * KCH;

    float* outp = out + (size_t)ks * PART_ELEMS;

    // Staging source (XOR-swizzled chunk). Same XOR term for rows r and r+64.
    const int grow = tid >> 2;
    const int gxor = (grow >> 1) & 3;
    const int gcol = ((tid & 3) ^ gxor) * 8;      // u16 units
    const u16* aS = xb + (size_t)(brow + grow) * K_ + k0 + gcol;

    // Fragment read offsets with matching XOR (invariant under row += 16).
    const int frow = lane & 15;
    const int fx = (frow >> 1) & 3;
    const int fk = (((lane >> 4) ^ fx)) * 8;
    const int aF = (wr * 64 + frow) * BK + fk;
    const int bF = (wc * 64 + frow) * BK + fk;

#define STAGE(t, buf)                                                  \
    do {                                                               \
        const u16* _a = aS + (size_t)(t) * BK;                         \
        const u16* _b = bS + (size_t)(t) * BK;                         \
        u16* _la = &As[buf][tid * 8];                                  \
        u16* _lb = &Bs[buf][tid * 8];                                  \
        gld16(_a, _la);                                                \
        gld16(_a + (size_t)64 * K_, _la + 2048);                       \
        gld16(_b, _lb);                                                \
        gld16(_b + (size_t)64 * K_, _lb + 2048);                       \
    } while (0)

    for (int e = 0; e < E_; ++e) {
        const int s = (e == 0) ? 0 : offs[e - 1];
        const int en = offs[e];
        if (en <= brow || s >= brow + BM) continue;  // block-uniform

        const u16* bS = wb + ((size_t)e * N_ + bcol + grow) * K_ + k0 + gcol;

        STAGE(0, 0);
        STAGE(1, 1);          // 8 loads in flight

        f32x4 acc[4][4];
#pragma unroll
        for (int m = 0; m < 4; ++m)
#pragma unroll
            for (int n = 0; n < 4; ++n)
                acc[m][n] = f32x4{0.0f, 0.0f, 0.0f, 0.0f};

        int cur = 0;
        for (int t = 0; t < NKS; ++t) {
            if (t + 2 < NKS) {
                int nb = cur + 2; if (nb >= 3) nb -= 3;
                STAGE(t + 2, nb);                       // 12 in flight
                asm volatile("s_waitcnt vmcnt(8)" ::: "memory");  // tile t landed
            } else if (t + 1 < NKS) {
                asm volatile("s_waitcnt vmcnt(4)" ::: "memory");
            } else {
                asm volatile("s_waitcnt vmcnt(0)" ::: "memory");
            }
            __builtin_amdgcn_sched_barrier(0);
            __builtin_amdgcn_s_barrier();    // all waves' tile-t writes visible

            bf16x8 af[4], bg[4];
#pragma unroll
            for (int m = 0; m < 4; ++m)
                af[m] = *(const bf16x8*)&As[cur][aF + m * 16 * BK];
#pragma unroll
            for (int n = 0; n < 4; ++n)
                bg[n] = *(const bf16x8*)&Bs[cur][bF + n * 16 * BK];

            __builtin_amdgcn_s_setprio(1);
#pragma unroll
            for (int m = 0; m < 4; ++m)
#pragma unroll
                for (int n = 0; n < 4; ++n)
                    acc[m][n] = __builtin_amdgcn_mfma_f32_16x16x32_bf16(
                        af[m], bg[n], acc[m][n], 0, 0, 0);
            __builtin_amdgcn_s_setprio(0);
            __builtin_amdgcn_s_barrier();    // reads done before buf reused
            cur = (cur + 1 == 3) ? 0 : cur + 1;
        }

        // C/D layout: col = lane&15, row = (lane>>4)*4 + reg
        const int cb = bcol + wc * 64 + frow;
#pragma unroll
        for (int m = 0; m < 4; ++m) {
            const int r0 = brow + wr * 64 + m * 16 + (lane >> 4) * 4;
#pragma unroll
            for (int r = 0; r < 4; ++r) {
                const int row = r0 + r;
                if (row < s || row >= en) continue;  // ragged-boundary mask
                float* yp = outp + (size_t)row * N_ + cb;
#pragma unroll
                for (int n = 0; n < 4; ++n) yp[n * 16] = acc[m][n][r];
            }
        }
        __syncthreads();  // uniform; protects LDS across expert passes
    }
#undef STAGE
}

// ---------------- fallback: fp32 reg-staging + atomicAdd (small ws) ----------------
__global__ __launch_bounds__(256, 3) void gg_fallback_kernel(
        const float* __restrict__ x, const float* __restrict__ w,
        const int* __restrict__ offs, float* __restrict__ out) {
    constexpr int KSPLIT = 2;
    constexpr int KCH = K_ / KSPLIT;
    constexpr int NKS = KCH / BK;
    __shared__ __align__(16) u16 As[2][BM * LSTR];
    __shared__ __align__(16) u16 Bs[2][BN * LSTR];

    const int tid = threadIdx.x;
    const int lane = tid & 63;
    const int wid = tid >> 6;
    const int wr = wid >> 1, wc = wid & 1;

    const int b = blockIdx.x;
    const int xcd = b & 7;
    const int inner = b >> 3;
    const int ks = inner >> 5;
    const int rem = inner & 31;
    const int by = xcd * 4 + (rem >> 3);
    const int bx = rem & 7;
    const int brow = by * BM;
    const int bcol = bx * BN;
    const int k0 = ks * KCH;

    const int srow = tid >> 2;
    const int scol = (tid & 3) * 8;
    const float* aB0 = x + (size_t)(brow + srow) * K_ + k0 + scol;
    const float* aB1 = aB0 + (size_t)64 * K_;
    const int ldsO0 = srow * LSTR + scol;
    const int ldsO1 = (srow + 64) * LSTR + scol;

    const int frow = lane & 15;
    const int fkk = (lane >> 4) * 8;
    const int aF = (wr * 64 + frow) * LSTR + fkk;
    const int bF = (wc * 64 + frow) * LSTR + fkk;

#define LOADT(t)                                                      \
    do {                                                              \
        const float* _a0 = aB0 + (t) * BK;                            \
        const float* _a1 = aB1 + (t) * BK;                            \
        const float* _b0 = bB0 + (t) * BK;                            \
        const float* _b1 = bB1 + (t) * BK;                            \
        ra0 = *(const f32x4*)_a0; ra1 = *(const f32x4*)(_a0 + 4);     \
        ra2 = *(const f32x4*)_a1; ra3 = *(const f32x4*)(_a1 + 4);     \
        rb0 = *(const f32x4*)_b0; rb1 = *(const f32x4*)(_b0 + 4);     \
        rb2 = *(const f32x4*)_b1; rb3 = *(const f32x4*)(_b1 + 4);     \
    } while (0)

#define STORET(buf)                                                   \
    do {                                                              \
        *(u32x4*)&As[buf][ldsO0] = cvt8(ra0, ra1);                    \
        *(u32x4*)&As[buf][ldsO1] = cvt8(ra2, ra3);                    \
        *(u32x4*)&Bs[buf][ldsO0] = cvt8(rb0, rb1);                    \
        *(u32x4*)&Bs[buf][ldsO1] = cvt8(rb2, rb3);                    \
    } while (0)

    for (int e = 0; e < E_; ++e) {
        const int s = (e == 0) ? 0 : offs[e - 1];
        const int en = offs[e];
        if (en <= brow || s >= brow + BM) continue;

        const float* bB0 = w + ((size_t)e * N_ + bcol + srow) * K_ + k0 + scol;
        const float* bB1 = bB0 + (size_t)64 * K_;

        f32x4 ra0, ra1, ra2, ra3, rb0, rb1, rb2, rb3;
        LOADT(0);
        STORET(0);
        LOADT(1);
        __syncthreads();

        f32x4 acc[4][4];
#pragma unroll
        for (int m = 0; m < 4; ++m)
#pragma unroll
            for (int n = 0; n < 4; ++n)
                acc[m][n] = f32x4{0.0f, 0.0f, 0.0f, 0.0f};

        for (int t = 0; t < NKS; ++t) {
            const int cur = t & 1;
            if (t + 1 < NKS) STORET(cur ^ 1);
            if (t + 2 < NKS) LOADT(t + 2);
            bf16x8 af[4], bg[4];
#pragma unroll
            for (int m = 0; m < 4; ++m)
                af[m] = *(const bf16x8*)&As[cur][aF + m * 16 * LSTR];
#pragma unroll
            for (int n = 0; n < 4; ++n)
                bg[n] = *(const bf16x8*)&Bs[cur][bF + n * 16 * LSTR];
#pragma unroll
            for (int m = 0; m < 4; ++m)
#pragma unroll
                for (int n = 0; n < 4; ++n)
                    acc[m][n] = __builtin_amdgcn_mfma_f32_16x16x32_bf16(
                        af[m], bg[n], acc[m][n], 0, 0, 0);
            __syncthreads();
        }

        const int cb = bcol + wc * 64 + frow;
#pragma unroll
        for (int m = 0; m < 4; ++m) {
            const int r0 = brow + wr * 64 + m * 16 + (lane >> 4) * 4;
#pragma unroll
            for (int r = 0; r < 4; ++r) {
                const int row = r0 + r;
                if (row < s || row >= en) continue;
                float* yp = out + (size_t)row * N_ + cb;
#pragma unroll
                for (int n = 0; n < 4; ++n) atomicAdd(&yp[n * 16], acc[m][n][r]);
            }
        }
        __syncthreads();
    }
#undef LOADT
#undef STORET
}

template <int P>
__global__ __launch_bounds__(256) void gg_reduce_kernel(
        const float* __restrict__ part, float* __restrict__ y) {
    const size_t i = (size_t)blockIdx.x * blockDim.x + threadIdx.x;  // f32x4 idx
    f32x4 acc = ((const f32x4*)part)[i];
#pragma unroll
    for (int p = 1; p < P; ++p)
        acc += ((const f32x4*)(part + (size_t)p * PART_ELEMS))[i];
    ((f32x4*)y)[i] = acc;
}

extern "C" void kernel_launch(void* const* d_in, const int* in_sizes, int n_in,
                              void* d_out, int out_size, void* d_ws, size_t ws_size,
                              hipStream_t stream) {
    const float* x = (const float*)d_in[0];
    const float* w = (const float*)d_in[1];
    const int* offs = (const int*)d_in[2];
    float* y = (float*)d_out;
    float* part = (float*)d_ws;
    const int rgrid = (int)(PART_ELEMS / 4 / 256);

    // ws layout: [2 partial planes f32 = 32 MB][xb 16 MB][wb 32 MB] = 80 MB
    const size_t need = 2 * PART_ELEMS * sizeof(float)
                      + (XB_ELEMS + WB_ELEMS) * sizeof(u16);

    if (ws_size >= need) {
        u16* xb = (u16*)(part + 2 * PART_ELEMS);
        u16* wb = xb + XB_ELEMS;
        cvt_all_kernel<<<dim3(2048), dim3(256), 0, stream>>>(
            x, w, (unsigned int*)xb, (unsigned int*)wb);
        gg_lds_kernel<2><<<dim3(512), dim3(256), 0, stream>>>(xb, wb, offs, part);
        gg_reduce_kernel<2><<<dim3(rgrid), dim3(256), 0, stream>>>(part, y);
    } else {
        hipMemsetAsync(d_out, 0, PART_ELEMS * sizeof(float), stream);
        gg_fallback_kernel<<<dim3(512), dim3(256), 0, stream>>>(x, w, offs, y);
    }
}

// Round 8
// 63.120 us; speedup vs baseline: 1.2305x; 1.0311x over previous
//
#include <hip/hip_runtime.h>
#include <hip/hip_bf16.h>

typedef __attribute__((ext_vector_type(4))) float f32x4;
typedef __attribute__((ext_vector_type(4))) unsigned int u32x4;
typedef __attribute__((ext_vector_type(8))) __bf16 bf16x8;
using u16 = unsigned short;

namespace {
constexpr int T_ = 4096;
constexpr int K_ = 2048;
constexpr int N_ = 1024;
constexpr int E_ = 8;
constexpr int BM = 128, BN = 128, BK = 32;
constexpr int LSTR = BK + 8;                     // fallback kernel LDS stride
constexpr size_t PART_ELEMS = (size_t)T_ * N_;   // 4M floats per partial plane
constexpr size_t XB_ELEMS = (size_t)T_ * K_;     // 8M bf16
constexpr size_t WB_ELEMS = (size_t)E_ * N_ * K_;// 16M bf16
constexpr int XB_UNITS = (int)(XB_ELEMS / 8);    // 1M u32x4 units
constexpr int WB_UNITS = (int)(WB_ELEMS / 8);    // 2M
constexpr int XB_BLOCKS = XB_UNITS / 256;        // 4096
constexpr int WB_BLOCKS = WB_UNITS / 256;        // 8192
}

__device__ __forceinline__ unsigned int pk2(float a, float b) {
    union { __hip_bfloat162 h; unsigned int u; } c;
    c.h = __float22bfloat162_rn(make_float2(a, b));   // v_cvt_pk_bf16_f32
    return c.u;
}

__device__ __forceinline__ u32x4 cvt8(f32x4 a, f32x4 b) {
    u32x4 r;
    r.x = pk2(a.x, a.y);
    r.y = pk2(a.z, a.w);
    r.z = pk2(b.x, b.y);
    r.w = pk2(b.z, b.w);
    return r;
}

__device__ __forceinline__ void gld16(const u16* g, u16* l) {
    __builtin_amdgcn_global_load_lds(
        (const __attribute__((address_space(1))) void*)g,
        (__attribute__((address_space(3))) void*)l, 16, 0, 0);
}

// ---------------- prepass: flat one-unit-per-thread fp32 -> bf16 ----------------
// Round-7's grid-stride loop (6 serial iters/thread + range branch) ran at
// 2.5 TB/s. Flat map: each thread converts exactly one u32x4 unit (32B read,
// 16B write), block-range split between x and w. No loop, no 64-bit div.
__global__ __launch_bounds__(256) void cvt_all_kernel(
        const float* __restrict__ x, const float* __restrict__ w,
        unsigned int* __restrict__ xb, unsigned int* __restrict__ wb) {
    const int b = blockIdx.x;
    if (b < XB_BLOCKS) {
        const size_t i = (size_t)b * 256 + threadIdx.x;
        const f32x4 a0 = ((const f32x4*)x)[2 * i];
        const f32x4 a1 = ((const f32x4*)x)[2 * i + 1];
        ((u32x4*)xb)[i] = cvt8(a0, a1);
    } else {
        const size_t j = (size_t)(b - XB_BLOCKS) * 256 + threadIdx.x;
        const f32x4 a0 = ((const f32x4*)w)[2 * j];
        const f32x4 a1 = ((const f32x4*)w)[2 * j + 1];
        ((u32x4*)wb)[j] = cvt8(a0, a1);
    }
}

// ---------------- main GEMM: counted-vmcnt 3-buffer pipeline (r7, unchanged) ----
template <int KSPLIT>
__global__ __launch_bounds__(256) void gg_lds_kernel(
        const u16* __restrict__ xb, const u16* __restrict__ wb,
        const int* __restrict__ offs, float* __restrict__ out) {
    constexpr int KCH = K_ / KSPLIT;
    constexpr int NKS = KCH / BK;                 // 32 at KSPLIT=2
    __shared__ __align__(16) u16 As[3][BM * BK];  // 3 x 8 KB
    __shared__ __align__(16) u16 Bs[3][BN * BK];  // 48 KB total

    const int tid = threadIdx.x;
    const int lane = tid & 63;
    const int wid = tid >> 6;
    const int wr = wid >> 1, wc = wid & 1;        // 2x2 waves, 64x64 out each

    const int b = blockIdx.x;
    const int xcd = b & 7;
    const int inner = b >> 3;
    const int ks = inner >> 5;
    const int rem = inner & 31;
    const int by = xcd * 4 + (rem >> 3);
    const int bx = rem & 7;
    const int brow = by * BM;
    const int bcol = bx * BN;
    const int k0 = ks * KCH;

    float* outp = out + (size_t)ks * PART_ELEMS;

    // Staging source (XOR-swizzled chunk). Same XOR term for rows r and r+64.
    const int grow = tid >> 2;
    const int gxor = (grow >> 1) & 3;
    const int gcol = ((tid & 3) ^ gxor) * 8;      // u16 units
    const u16* aS = xb + (size_t)(brow + grow) * K_ + k0 + gcol;

    // Fragment read offsets with matching XOR (invariant under row += 16).
    const int frow = lane & 15;
    const int fx = (frow >> 1) & 3;
    const int fk = (((lane >> 4) ^ fx)) * 8;
    const int aF = (wr * 64 + frow) * BK + fk;
    const int bF = (wc * 64 + frow) * BK + fk;

#define STAGE(t, buf)                                                  \
    do {                                                               \
        const u16* _a = aS + (size_t)(t) * BK;                         \
        const u16* _b = bS + (size_t)(t) * BK;                         \
        u16* _la = &As[buf][tid * 8];                                  \
        u16* _lb = &Bs[buf][tid * 8];                                  \
        gld16(_a, _la);                                                \
        gld16(_a + (size_t)64 * K_, _la + 2048);                       \
        gld16(_b, _lb);                                                \
        gld16(_b + (size_t)64 * K_, _lb + 2048);                       \
    } while (0)

    for (int e = 0; e < E_; ++e) {
        const int s = (e == 0) ? 0 : offs[e - 1];
        const int en = offs[e];
        if (en <= brow || s >= brow + BM) continue;  // block-uniform

        const u16* bS = wb + ((size_t)e * N_ + bcol + grow) * K_ + k0 + gcol;

        STAGE(0, 0);
        STAGE(1, 1);          // 8 loads in flight

        f32x4 acc[4][4];
#pragma unroll
        for (int m = 0; m < 4; ++m)
#pragma unroll
            for (int n = 0; n < 4; ++n)
                acc[m][n] = f32x4{0.0f, 0.0f, 0.0f, 0.0f};

        int cur = 0;
        for (int t = 0; t < NKS; ++t) {
            if (t + 2 < NKS) {
                int nb = cur + 2; if (nb >= 3) nb -= 3;
                STAGE(t + 2, nb);                       // 12 in flight
                asm volatile("s_waitcnt vmcnt(8)" ::: "memory");  // tile t landed
            } else if (t + 1 < NKS) {
                asm volatile("s_waitcnt vmcnt(4)" ::: "memory");
            } else {
                asm volatile("s_waitcnt vmcnt(0)" ::: "memory");
            }
            __builtin_amdgcn_sched_barrier(0);
            __builtin_amdgcn_s_barrier();    // all waves' tile-t writes visible

            bf16x8 af[4], bg[4];
#pragma unroll
            for (int m = 0; m < 4; ++m)
                af[m] = *(const bf16x8*)&As[cur][aF + m * 16 * BK];
#pragma unroll
            for (int n = 0; n < 4; ++n)
                bg[n] = *(const bf16x8*)&Bs[cur][bF + n * 16 * BK];

            __builtin_amdgcn_s_setprio(1);
#pragma unroll
            for (int m = 0; m < 4; ++m)
#pragma unroll
                for (int n = 0; n < 4; ++n)
                    acc[m][n] = __builtin_amdgcn_mfma_f32_16x16x32_bf16(
                        af[m], bg[n], acc[m][n], 0, 0, 0);
            __builtin_amdgcn_s_setprio(0);
            __builtin_amdgcn_s_barrier();    // reads done before buf reused
            cur = (cur + 1 == 3) ? 0 : cur + 1;
        }

        // C/D layout: col = lane&15, row = (lane>>4)*4 + reg
        const int cb = bcol + wc * 64 + frow;
#pragma unroll
        for (int m = 0; m < 4; ++m) {
            const int r0 = brow + wr * 64 + m * 16 + (lane >> 4) * 4;
#pragma unroll
            for (int r = 0; r < 4; ++r) {
                const int row = r0 + r;
                if (row < s || row >= en) continue;  // ragged-boundary mask
                float* yp = outp + (size_t)row * N_ + cb;
#pragma unroll
                for (int n = 0; n < 4; ++n) yp[n * 16] = acc[m][n][r];
            }
        }
        __syncthreads();  // uniform; protects LDS across expert passes
    }
#undef STAGE
}

// ---------------- fallback: fp32 reg-staging + atomicAdd (small ws) ----------------
__global__ __launch_bounds__(256, 3) void gg_fallback_kernel(
        const float* __restrict__ x, const float* __restrict__ w,
        const int* __restrict__ offs, float* __restrict__ out) {
    constexpr int KSPLIT = 2;
    constexpr int KCH = K_ / KSPLIT;
    constexpr int NKS = KCH / BK;
    __shared__ __align__(16) u16 As[2][BM * LSTR];
    __shared__ __align__(16) u16 Bs[2][BN * LSTR];

    const int tid = threadIdx.x;
    const int lane = tid & 63;
    const int wid = tid >> 6;
    const int wr = wid >> 1, wc = wid & 1;

    const int b = blockIdx.x;
    const int xcd = b & 7;
    const int inner = b >> 3;
    const int ks = inner >> 5;
    const int rem = inner & 31;
    const int by = xcd * 4 + (rem >> 3);
    const int bx = rem & 7;
    const int brow = by * BM;
    const int bcol = bx * BN;
    const int k0 = ks * KCH;

    const int srow = tid >> 2;
    const int scol = (tid & 3) * 8;
    const float* aB0 = x + (size_t)(brow + srow) * K_ + k0 + scol;
    const float* aB1 = aB0 + (size_t)64 * K_;
    const int ldsO0 = srow * LSTR + scol;
    const int ldsO1 = (srow + 64) * LSTR + scol;

    const int frow = lane & 15;
    const int fkk = (lane >> 4) * 8;
    const int aF = (wr * 64 + frow) * LSTR + fkk;
    const int bF = (wc * 64 + frow) * LSTR + fkk;

#define LOADT(t)                                                      \
    do {                                                              \
        const float* _a0 = aB0 + (t) * BK;                            \
        const float* _a1 = aB1 + (t) * BK;                            \
        const float* _b0 = bB0 + (t) * BK;                            \
        const float* _b1 = bB1 + (t) * BK;                            \
        ra0 = *(const f32x4*)_a0; ra1 = *(const f32x4*)(_a0 + 4);     \
        ra2 = *(const f32x4*)_a1; ra3 = *(const f32x4*)(_a1 + 4);     \
        rb0 = *(const f32x4*)_b0; rb1 = *(const f32x4*)(_b0 + 4);     \
        rb2 = *(const f32x4*)_b1; rb3 = *(const f32x4*)(_b1 + 4);     \
    } while (0)

#define STORET(buf)                                                   \
    do {                                                              \
        *(u32x4*)&As[buf][ldsO0] = cvt8(ra0, ra1);                    \
        *(u32x4*)&As[buf][ldsO1] = cvt8(ra2, ra3);                    \
        *(u32x4*)&Bs[buf][ldsO0] = cvt8(rb0, rb1);                    \
        *(u32x4*)&Bs[buf][ldsO1] = cvt8(rb2, rb3);                    \
    } while (0)

    for (int e = 0; e < E_; ++e) {
        const int s = (e == 0) ? 0 : offs[e - 1];
        const int en = offs[e];
        if (en <= brow || s >= brow + BM) continue;

        const float* bB0 = w + ((size_t)e * N_ + bcol + srow) * K_ + k0 + scol;
        const float* bB1 = bB0 + (size_t)64 * K_;

        f32x4 ra0, ra1, ra2, ra3, rb0, rb1, rb2, rb3;
        LOADT(0);
        STORET(0);
        LOADT(1);
        __syncthreads();

        f32x4 acc[4][4];
#pragma unroll
        for (int m = 0; m < 4; ++m)
#pragma unroll
            for (int n = 0; n < 4; ++n)
                acc[m][n] = f32x4{0.0f, 0.0f, 0.0f, 0.0f};

        for (int t = 0; t < NKS; ++t) {
            const int cur = t & 1;
            if (t + 1 < NKS) STORET(cur ^ 1);
            if (t + 2 < NKS) LOADT(t + 2);
            bf16x8 af[4], bg[4];
#pragma unroll
            for (int m = 0; m < 4; ++m)
                af[m] = *(const bf16x8*)&As[cur][aF + m * 16 * LSTR];
#pragma unroll
            for (int n = 0; n < 4; ++n)
                bg[n] = *(const bf16x8*)&Bs[cur][bF + n * 16 * LSTR];
#pragma unroll
            for (int m = 0; m < 4; ++m)
#pragma unroll
                for (int n = 0; n < 4; ++n)
                    acc[m][n] = __builtin_amdgcn_mfma_f32_16x16x32_bf16(
                        af[m], bg[n], acc[m][n], 0, 0, 0);
            __syncthreads();
        }

        const int cb = bcol + wc * 64 + frow;
#pragma unroll
        for (int m = 0; m < 4; ++m) {
            const int r0 = brow + wr * 64 + m * 16 + (lane >> 4) * 4;
#pragma unroll
            for (int r = 0; r < 4; ++r) {
                const int row = r0 + r;
                if (row < s || row >= en) continue;
                float* yp = out + (size_t)row * N_ + cb;
#pragma unroll
                for (int n = 0; n < 4; ++n) atomicAdd(&yp[n * 16], acc[m][n][r]);
            }
        }
        __syncthreads();
    }
#undef LOADT
#undef STORET
}

template <int P>
__global__ __launch_bounds__(256) void gg_reduce_kernel(
        const float* __restrict__ part, float* __restrict__ y) {
    const size_t i = (size_t)blockIdx.x * blockDim.x + threadIdx.x;  // f32x4 idx
    f32x4 acc = ((const f32x4*)part)[i];
#pragma unroll
    for (int p = 1; p < P; ++p)
        acc += ((const f32x4*)(part + (size_t)p * PART_ELEMS))[i];
    ((f32x4*)y)[i] = acc;
}

extern "C" void kernel_launch(void* const* d_in, const int* in_sizes, int n_in,
                              void* d_out, int out_size, void* d_ws, size_t ws_size,
                              hipStream_t stream) {
    const float* x = (const float*)d_in[0];
    const float* w = (const float*)d_in[1];
    const int* offs = (const int*)d_in[2];
    float* y = (float*)d_out;
    float* part = (float*)d_ws;
    const int rgrid = (int)(PART_ELEMS / 4 / 256);

    // ws layout: [2 partial planes f32 = 32 MB][xb 16 MB][wb 32 MB] = 80 MB
    const size_t need = 2 * PART_ELEMS * sizeof(float)
                      + (XB_ELEMS + WB_ELEMS) * sizeof(u16);

    if (ws_size >= need) {
        u16* xb = (u16*)(part + 2 * PART_ELEMS);
        u16* wb = xb + XB_ELEMS;
        cvt_all_kernel<<<dim3(XB_BLOCKS + WB_BLOCKS), dim3(256), 0, stream>>>(
            x, w, (unsigned int*)xb, (unsigned int*)wb);
        gg_lds_kernel<2><<<dim3(512), dim3(256), 0, stream>>>(xb, wb, offs, part);
        gg_reduce_kernel<2><<<dim3(rgrid), dim3(256), 0, stream>>>(part, y);
    } else {
        hipMemsetAsync(d_out, 0, PART_ELEMS * sizeof(float), stream);
        gg_fallback_kernel<<<dim3(512), dim3(256), 0, stream>>>(x, w, offs, y);
    }
}